// Round 6
// baseline (139.907 us; speedup 1.0000x reference)
//
#include <hip/hip_runtime.h>
#include <hip/hip_bf16.h>
#include <math.h>

// Problem constants (B, Cin, Cmid, H, W) = (2, 256, 128, 112, 112), R=3
constexpr int B    = 2;
constexpr int CIN  = 256;
constexpr int CMID = 128;
constexpr int H    = 112;
constexpr int W    = 112;
constexpr int HW   = H * W;        // 12544
constexpr int NPIX = B * HW;       // 25088
constexpr int RAD  = 3;
constexpr int KS   = 7;
constexpr int DD   = 49;

typedef __attribute__((ext_vector_type(8))) short  short8;   // 8 bf16 (4 VGPR)
typedef __attribute__((ext_vector_type(4))) float  float4v;  // MFMA C/D

// RNE fp32-pair -> packed bf16x2 via v_cvt_pk_bf16_f32 (compiler-lowered)
__device__ __forceinline__ unsigned pkbf(float a, float b) {
    __hip_bfloat162 h = __float22bfloat162_rn(make_float2(a, b));
    union { __hip_bfloat162 h2; unsigned u; } c;
    c.h2 = h;
    return c.u;
}

// ---------------------------------------------------------------------------
// Kernel 1: q = l2norm(Wq @ phi_cur), k = l2norm(Wk @ phi_rnd)  via bf16 MFMA.
// R5 structure (best measured) with prep FOLDED IN (3 launches -> 2):
//  - A-frags built from f32 W directly, TWO pre-staging chunks of
//    {16 float4 loads -> cvt_pk}: peak VGPR ~106 < 128 cap; same RNE
//    conversion as the old prep kernel -> identical numerics.
//  - spare block (x == NPIX/64) writes the padded Wv table wvp instead;
//    consumed only by corr (next launch) -> no race.
//  - staging keeps R5's issue-early/write-late split (2 batches);
//    A-frag chunk loads issue first and drain during staging/barrier.
// LDS: pixel-major bf16, PSTR=264 shorts, col XOR-swizzle ((pix>>3)&3)<<3:
// staging b32 writes 2-way (free, m136), frag b128 reads at the structural
// optimum.  __launch_bounds__(256,4): 4 blocks/CU, all 784 co-resident.
// ---------------------------------------------------------------------------
constexpr int PSTR = 264;           // shorts per pixel row in pt

__global__ __launch_bounds__(256, 4) void proj_mfma(
    const float* __restrict__ phi_cur, const float* __restrict__ phi_rnd,
    const float* __restrict__ Wq, const float* __restrict__ Wk,
    const float* __restrict__ Wv,
    unsigned short* __restrict__ q_ws, unsigned short* __restrict__ k_ws,
    float* __restrict__ wvp)
{
    const int tid  = threadIdx.x;
    const int t    = blockIdx.y;                    // 0 -> q, 1 -> k

    if (blockIdx.x == NPIX / 64) {                  // side block: wvp prep
        if (t == 0)
            for (int idx = tid; idx < DD * 52; idx += 256) {
                const int r = idx / 52, c = idx % 52;
                wvp[idx] = (c < DD) ? Wv[r * DD + c] : 0.f;
            }
        return;
    }

    __shared__ unsigned short pt[64 * PSTR];  // 33,792 B  pixel-major bf16
    __shared__ float red[4][64];

    const int lane = tid & 63;
    const int wv   = __builtin_amdgcn_readfirstlane(tid >> 6);

    const float* __restrict__ phi = t ? phi_rnd : phi_cur;
    const float* __restrict__ Wf  = t ? Wk : Wq;
    unsigned short* __restrict__ outp = t ? k_ws : q_ws;

    const int pgb = blockIdx.x * 64;                // 64-aligned, no b crossing
    const int b   = pgb / HW;
    const int pim = pgb % HW;
    const float* pbase = phi + (size_t)b * CIN * HW + pim;

    const int m = lane & 15, quad = lane >> 4;

    // ---- A-frags from f32 W (L2-hot): 2 chunks x {16 f4 loads, cvt_pk} ----
    short8 af[2][8];
#pragma unroll
    for (int ot = 0; ot < 2; ++ot) {
        float4 wt[16];
        const float* wr = Wf + (size_t)(wv * 32 + ot * 16 + m) * CIN + quad * 8;
#pragma unroll
        for (int kc = 0; kc < 8; ++kc) {
            wt[2 * kc]     = *(const float4*)(wr + kc * 32);
            wt[2 * kc + 1] = *(const float4*)(wr + kc * 32 + 4);
        }
#pragma unroll
        for (int kc = 0; kc < 8; ++kc) {
            union { short8 s; unsigned u[4]; } cv;
            cv.u[0] = pkbf(wt[2 * kc].x,     wt[2 * kc].y);
            cv.u[1] = pkbf(wt[2 * kc].z,     wt[2 * kc].w);
            cv.u[2] = pkbf(wt[2 * kc + 1].x, wt[2 * kc + 1].y);
            cv.u[3] = pkbf(wt[2 * kc + 1].z, wt[2 * kc + 1].w);
            af[ot][kc] = cv.s;
        }
    }

    // ---- stage phi tile: 2 batches x {issue 8 f4 loads, pack+write} ----
#pragma unroll
    for (int half = 0; half < 2; ++half) {
        float4 va[4], vb[4];
#pragma unroll
        for (int p = 0; p < 4; ++p) {
            const int idx = (half * 4 + p) * 256 + tid;
            const int cp  = idx >> 4;          // channel pair 0..127
            const int pq  = idx & 15;          // pixel quad  0..15
            const int c0  = cp * 2;
            va[p] = *(const float4*)(pbase + (size_t)c0 * HW + pq * 4);
            vb[p] = *(const float4*)(pbase + (size_t)(c0 + 1) * HW + pq * 4);
        }
#pragma unroll
        for (int p = 0; p < 4; ++p) {
            const int idx = (half * 4 + p) * 256 + tid;
            const int cp  = idx >> 4;
            const int pq  = idx & 15;
            const int c0  = cp * 2;
            const int swz = ((pq >> 1) & 3) << 3;        // == ((pix>>3)&3)<<3
            const int col = c0 ^ swz;
            *(unsigned*)(pt + (pq * 4 + 0) * PSTR + col) = pkbf(va[p].x, vb[p].x);
            *(unsigned*)(pt + (pq * 4 + 1) * PSTR + col) = pkbf(va[p].y, vb[p].y);
            *(unsigned*)(pt + (pq * 4 + 2) * PSTR + col) = pkbf(va[p].z, vb[p].z);
            *(unsigned*)(pt + (pq * 4 + 3) * PSTR + col) = pkbf(va[p].w, vb[p].w);
        }
    }

    __syncthreads();

    // ---- MFMA: 2 out-tiles x 4 pixel-tiles x K=256 (af already resident) ----
    float4v acc[2][4];
#pragma unroll
    for (int ot = 0; ot < 2; ++ot)
#pragma unroll
        for (int nt = 0; nt < 4; ++nt) acc[ot][nt] = (float4v)0.f;

#pragma unroll
    for (int kc = 0; kc < 8; ++kc) {
        short8 bfr[4];
#pragma unroll
        for (int nt = 0; nt < 4; ++nt) {
            const int row = nt * 16 + m;
            const int col = (kc * 32 + quad * 8) ^ (((row >> 3) & 3) << 3);
            bfr[nt] = *(const short8*)(pt + row * PSTR + col);
        }
#pragma unroll
        for (int nt = 0; nt < 4; ++nt) {
            acc[0][nt] = __builtin_amdgcn_mfma_f32_16x16x32_bf16(af[0][kc], bfr[nt], acc[0][nt], 0, 0, 0);
            acc[1][nt] = __builtin_amdgcn_mfma_f32_16x16x32_bf16(af[1][kc], bfr[nt], acc[1][nt], 0, 0, 0);
        }
    }

    // ---- per-pixel L2 norm: C layout col=lane&15=pixel, row=quad*4+reg=och
#pragma unroll
    for (int nt = 0; nt < 4; ++nt) {
        float ss = 0.f;
#pragma unroll
        for (int ot = 0; ot < 2; ++ot)
#pragma unroll
            for (int r = 0; r < 4; ++r)
                ss = fmaf(acc[ot][nt][r], acc[ot][nt][r], ss);
        ss += __shfl_xor(ss, 16, 64);
        ss += __shfl_xor(ss, 32, 64);
        if (quad == 0) red[wv][nt * 16 + m] = ss;
    }
    __syncthreads();

    float inv[4];
#pragma unroll
    for (int nt = 0; nt < 4; ++nt) {
        const int px = nt * 16 + m;
        const float tot = red[0][px] + red[1][px] + red[2][px] + red[3][px];
        inv[nt] = 1.f / fmaxf(sqrtf(tot), 1e-12f);
    }

    // ---- store bf16 pixel-major ----
#pragma unroll
    for (int nt = 0; nt < 4; ++nt)
#pragma unroll
        for (int ot = 0; ot < 2; ++ot) {
            uint2 st;
            st.x = pkbf(acc[ot][nt][0] * inv[nt], acc[ot][nt][1] * inv[nt]);
            st.y = pkbf(acc[ot][nt][2] * inv[nt], acc[ot][nt][3] * inv[nt]);
            *(uint2*)(outp + (size_t)(pgb + nt * 16 + m) * CMID
                      + wv * 32 + ot * 16 + quad * 4) = st;
        }
}

// ---------------------------------------------------------------------------
// Kernel 2: correlation -- NO INPUT STAGING (common-mistake #7: q_ws/k_ws are
// 12.8 MB each, L2-resident and freshly written by proj; staging them in LDS
// was pure overhead).  Phase B loads A-frags (q) and B-frags (k) DIRECTLY
// from global with per-lane zero-predication for the zero-padded halo,
// 1-deep pipelined across the wave's 3-4 groups.  LDS shrinks 49.6 -> 7.4 KB
// (cs + ls only) and the kernel has ONE barrier (cs cross-wave handoff).
// Geometry + aq/b-frag loads issue before the group loop so L2 latency
// overlaps VALU; wq4 (52 VGPR) loads after the barrier to cap pressure.
// XCD-chunked bijective block swizzle keeps the k halo in-XCD-L2.
// ---------------------------------------------------------------------------
constexpr int TILE = 16;
constexpr int COLS = TILE + 6;      // 22

__global__ __launch_bounds__(256, 4) void corr_kernel(
    const unsigned short* __restrict__ q_ws, const unsigned short* __restrict__ k_ws,
    const float* __restrict__ P_cur, const float* __restrict__ P_rnd,
    const float* __restrict__ wvp, const float* __restrict__ bv,
    const float* __restrict__ gamma_p, float* __restrict__ out)
{
    __shared__ alignas(16) float cs[TILE][52];   // 3,328 B corr vectors
    __shared__ alignas(16) float lsf[TILE][64];  // 4,096 B logit rows

    const int tid  = threadIdx.x;
    const int lane = tid & 63;
    const int wv   = __builtin_amdgcn_readfirstlane(tid >> 6);

    // ---- XCD-chunked bijective swizzle: fid -> contiguous 196-block chunk --
    const int fid = (blockIdx.z * H + blockIdx.y) * (W / TILE) + blockIdx.x;
    const int swz = (fid & 7) * 196 + (fid >> 3);
    const int b   = swz / (H * (W / TILE));
    const int rem = swz % (H * (W / TILE));
    const int h   = rem / (W / TILE);
    const int w0  = (rem % (W / TILE)) * TILE;

    const int m = lane & 15, quad = lane >> 4;

    // ---- A-frags: q rows for the 16 pixels, straight from L2 ----
    const size_t qbase = (size_t)b * HW + h * W + w0;
    short8 aq[4];
#pragma unroll
    for (int kc = 0; kc < 4; ++kc)
        aq[kc] = *(const short8*)(q_ws + (qbase + m) * CMID + kc * 32 + quad * 8);

    // ---- B-frag loader: group g -> k vector (zero for padded halo) ----
    auto loadB = [&](int g, short8* dst) {
        const int r   = g >> 1, nt2 = g & 1;
        const int cc  = nt2 * 16 + m;
        const int hh  = h + r - RAD;
        const int ww  = w0 + cc - RAD;
        const bool ok = (unsigned)hh < (unsigned)H && (unsigned)ww < (unsigned)W
                        && cc < COLS;
        const unsigned short* kp = k_ws
            + ((size_t)b * HW + (ok ? hh * W + ww : 0)) * CMID + quad * 8;
#pragma unroll
        for (int kc = 0; kc < 4; ++kc) {
            short8 v = *(const short8*)(kp + kc * 32);
            dst[kc] = ok ? v : (short8)(short)0;
        }
    };

    short8 bcur[4], bnxt[4];
    loadB(wv, bcur);                              // group 0 in flight

    // zero the cs padding (cols 49..51); ordered by the barrier below
    if (tid < TILE * 3)
        cs[tid / 3][49 + tid % 3] = 0.f;

    // ---- geometry (overlaps the loads above) ----
    const int  ld    = (lane < DD) ? lane : 0;
    const bool valid = (lane < DD);
    const float gamma = gamma_p[0];
    const float bvv   = bv[ld];
    const int dy = ld / KS - RAD;
    const int dx = ld % KS - RAD;
    float geo[4];
#pragma unroll
    for (int i = 0; i < 4; ++i) {
        const int pl = wv * 4 + i;      // pixel local 0..15
        const int hn = h + dy, wn = w0 + pl + dx;
        const bool inb = valid && hn >= 0 && hn < H && wn >= 0 && wn < W;
        const float* pc = P_cur + (size_t)b * 3 * HW + (h * W + w0 + pl);
        const float cx = pc[0], cy = pc[HW], cz = pc[2 * HW];
        float rx = 0.f, ry = 0.f, rz = 0.f;
        if (inb) {
            const float* pr = P_rnd + (size_t)b * 3 * HW + (hn * W + wn);
            rx = pr[0]; ry = pr[HW]; rz = pr[2 * HW];
        }
        const float dpx = cx - rx, dpy = cy - ry, dpz = cz - rz;
        const float dist = sqrtf(fmaxf(dpx * dpx + dpy * dpy + dpz * dpz, 1e-12f));
        geo[i] = gamma * (-dist - 0.5f * fabsf(dpz));
    }

    // ---- phase B: band-GEMM, 1-deep pipelined over the wave's groups ----
#pragma unroll
    for (int gi = 0; gi < 4; ++gi) {
        const int g = wv + gi * 4;
        if (g < 14) {                              // wave-uniform guard
            if (g + 4 < 14) loadB(g + 4, bnxt);
            // 2 independent MFMA chains, then merge
            float4v a0 = (float4v)0.f, a1 = (float4v)0.f;
            a0 = __builtin_amdgcn_mfma_f32_16x16x32_bf16(aq[0], bcur[0], a0, 0, 0, 0);
            a1 = __builtin_amdgcn_mfma_f32_16x16x32_bf16(aq[2], bcur[2], a1, 0, 0, 0);
            a0 = __builtin_amdgcn_mfma_f32_16x16x32_bf16(aq[1], bcur[1], a0, 0, 0, 0);
            a1 = __builtin_amdgcn_mfma_f32_16x16x32_bf16(aq[3], bcur[3], a1, 0, 0, 0);
#pragma unroll
            for (int r4 = 0; r4 < 4; ++r4) a0[r4] += a1[r4];
            // band extract: D row = pixel = quad*4+reg, col cc = (g&1)*16+m
            const int r   = g >> 1;
            const int cc  = (g & 1) * 16 + m;
#pragma unroll
            for (int reg = 0; reg < 4; ++reg) {
                const int p   = quad * 4 + reg;
                const int off = cc - p;            // dx + RAD
                if (off >= 0 && off <= 6)
                    cs[p][r * 7 + off] = a0[reg];
            }
#pragma unroll
            for (int kc = 0; kc < 4; ++kc) bcur[kc] = bnxt[kc];
        }
    }

    __syncthreads();                               // the kernel's ONE barrier

    // ---- phase C1: Wv dot + geo (lane = d); write logit rows to lsf ----
    float4 wq4[13];
#pragma unroll
    for (int j = 0; j < 13; ++j)
        wq4[j] = *(const float4*)(wvp + ld * 52 + j * 4);

#pragma unroll
    for (int i = 0; i < 4; ++i) {
        const int pl = wv * 4 + i;      // pixel local 0..15
        float logit = -INFINITY;
        if (valid) {
            float va0 = bvv, va1 = 0.f;     // dual independent FMA chains
#pragma unroll
            for (int e4 = 0; e4 < 13; ++e4) {
                const float4 c4 = *(const float4*)&cs[pl][e4 * 4];
                const float4 w4 = wq4[e4];
                if (e4 & 1) {
                    va1 = fmaf(w4.x, c4.x, va1);
                    va1 = fmaf(w4.y, c4.y, va1);
                    va1 = fmaf(w4.z, c4.z, va1);
                    va1 = fmaf(w4.w, c4.w, va1);
                } else {
                    va0 = fmaf(w4.x, c4.x, va0);
                    va0 = fmaf(w4.y, c4.y, va0);
                    va0 = fmaf(w4.z, c4.z, va0);
                    va0 = fmaf(w4.w, c4.w, va0);
                }
            }
            logit = (va0 + va1) + geo[i];
        }
        lsf[pl][lane] = logit;          // lanes 49..63 store -inf
    }

    // ---- phase C2: transposed in-wave softmax (lane = pixel x col-quad) ----
    // Same-wave LDS write->read: compiler-ordered via lgkmcnt, no barrier.
    {
        const int pli = lane >> 4;      // 0..3 within wave
        const int dq  = lane & 15;      // column quad (cols dq*4 .. dq*4+3)
        const int pl  = wv * 4 + pli;

        const float4 v = *(const float4*)&lsf[pl][dq * 4];

        float m4 = fmaxf(fmaxf(v.x, v.y), fmaxf(v.z, v.w));
#pragma unroll
        for (int s = 1; s < 16; s <<= 1)
            m4 = fmaxf(m4, __shfl_xor(m4, s, 64));

        const float e0 = __expf(v.x - m4);
        const float e1 = __expf(v.y - m4);
        const float e2 = __expf(v.z - m4);
        const float e3 = __expf(v.w - m4);
        float Z = (e0 + e1) + (e2 + e3);

        // dx = col%7-3, dy = col/7-3  (cols >= 49 have e == 0, values moot)
        const int c0i = dq * 4;
        float dus = 0.f, dvs = 0.f;
        {
            const float ex[4] = { e0, e1, e2, e3 };
#pragma unroll
            for (int j = 0; j < 4; ++j) {
                const int col = c0i + j;
                dus = fmaf(ex[j], (float)(col % KS - RAD), dus);
                dvs = fmaf(ex[j], (float)(col / KS - RAD), dvs);
            }
        }
#pragma unroll
        for (int s = 1; s < 16; s <<= 1) {
            Z   += __shfl_xor(Z,   s, 64);
            dus += __shfl_xor(dus, s, 64);
            dvs += __shfl_xor(dvs, s, 64);
        }

        if (dq == 0) {
            const int pg = b * HW + h * W + w0 + pl;
            const float invZ = 1.f / Z;
            out[pg]            = dus * invZ;
            out[NPIX + pg]     = dvs * invZ;
            out[2 * NPIX + pg] = invZ;       // conf = max w = exp(lmax-lmax)/Z
        }
    }
}

// ---------------------------------------------------------------------------
extern "C" void kernel_launch(void* const* d_in, const int* in_sizes, int n_in,
                              void* d_out, int out_size, void* d_ws, size_t ws_size,
                              hipStream_t stream)
{
    const float* phi_cur = (const float*)d_in[0];
    const float* phi_rnd = (const float*)d_in[1];
    const float* P_cur   = (const float*)d_in[2];
    const float* P_rnd   = (const float*)d_in[3];
    const float* Wq      = (const float*)d_in[4];
    const float* Wk      = (const float*)d_in[5];
    const float* Wv      = (const float*)d_in[6];
    const float* bv      = (const float*)d_in[7];
    const float* gm      = (const float*)d_in[8];
    float* out = (float*)d_out;

    unsigned short* ws   = (unsigned short*)d_ws;
    unsigned short* q_ws = ws;                                  // NPIX*CMID bf16
    unsigned short* k_ws = q_ws + (size_t)NPIX * CMID;          // NPIX*CMID bf16
    float*          wvp  = (float*)(k_ws + (size_t)NPIX * CMID); // 49x52 f32 (16B-aligned)

    proj_mfma<<<dim3(NPIX / 64 + 1, 2), 256, 0, stream>>>(
        phi_cur, phi_rnd, Wq, Wk, Wv, q_ws, k_ws, wvp);

    corr_kernel<<<dim3(W / TILE, H, B), 256, 0, stream>>>(
        q_ws, k_ws, P_cur, P_rnd, wvp, bv, gm, out);
}

// Round 7
// 137.621 us; speedup vs baseline: 1.0166x; 1.0166x over previous
//
#include <hip/hip_runtime.h>
#include <hip/hip_bf16.h>
#include <math.h>

// Problem constants (B, Cin, Cmid, H, W) = (2, 256, 128, 112, 112), R=3
constexpr int B    = 2;
constexpr int CIN  = 256;
constexpr int CMID = 128;
constexpr int H    = 112;
constexpr int W    = 112;
constexpr int HW   = H * W;        // 12544
constexpr int NPIX = B * HW;       // 25088
constexpr int RAD  = 3;
constexpr int KS   = 7;
constexpr int DD   = 49;

typedef __attribute__((ext_vector_type(8))) short  short8;   // 8 bf16 (4 VGPR)
typedef __attribute__((ext_vector_type(4))) float  float4v;  // MFMA C/D

// RNE fp32-pair -> packed bf16x2 via v_cvt_pk_bf16_f32 (compiler-lowered)
__device__ __forceinline__ unsigned pkbf(float a, float b) {
    __hip_bfloat162 h = __float22bfloat162_rn(make_float2(a, b));
    union { __hip_bfloat162 h2; unsigned u; } c;
    c.h2 = h;
    return c.u;
}

// ---------------------------------------------------------------------------
// Kernel 0 (prep, tiny): Wq/Wk f32 -> bf16; Wv f32 -> padded f32 [49][52].
// Kept SEPARATE: R6 folded this into proj (f32 W + 64-VGPR staging array)
// and regressed +7.5us -- spill past the 128-VGPR launch_bounds cap.
// ---------------------------------------------------------------------------
__global__ __launch_bounds__(256) void prep(
    const float* __restrict__ Wq, const float* __restrict__ Wk,
    const float* __restrict__ Wv,
    unsigned short* __restrict__ wqb, unsigned short* __restrict__ wkb,
    float* __restrict__ wvp)
{
    if (blockIdx.x < 64) {
        const int i  = blockIdx.x * 256 + threadIdx.x;   // float4 index
        const int n4 = (CMID * CIN) / 4;                 // 8192 per matrix
        const float4 v = (i < n4) ? ((const float4*)Wq)[i] : ((const float4*)Wk)[i - n4];
        uint2 r;
        r.x = pkbf(v.x, v.y);
        r.y = pkbf(v.z, v.w);
        if (i < n4) ((uint2*)wqb)[i] = r;
        else        ((uint2*)wkb)[i - n4] = r;
    } else {
        for (int idx = threadIdx.x; idx < DD * 52; idx += 256) {
            const int r = idx / 52, c = idx % 52;
            wvp[idx] = (c < DD) ? Wv[r * DD + c] : 0.f;
        }
    }
}

// ---------------------------------------------------------------------------
// Kernel 1: q = l2norm(Wq @ phi_cur), k = l2norm(Wk @ phi_rnd)  via bf16 MFMA.
// EXACT R5 kernel (best measured, 132.4):
//  (1) A-frags (16 x b128, L2-hot bf16 W) issued FIRST -- compiler cannot
//      hoist loads across __syncthreads; pre-barrier issue hides ~200cyc
//      under staging + barrier wait.  K-loop pure {4 ds_read + 8 MFMA}.
//  (2) staging split issue-early/write-late (T14): 2 batches of 8 float4
//      loads in flight, then pack/write.
// LDS: pixel-major bf16, PSTR=264, col XOR-swizzle ((pix>>3)&3)<<3.
// __launch_bounds__(256,4): 4 blocks/CU, all 784 co-resident.
// ---------------------------------------------------------------------------
constexpr int PSTR = 264;           // shorts per pixel row in pt

__global__ __launch_bounds__(256, 4) void proj_mfma(
    const float* __restrict__ phi_cur, const float* __restrict__ phi_rnd,
    const unsigned short* __restrict__ wq_bf, const unsigned short* __restrict__ wk_bf,
    unsigned short* __restrict__ q_ws, unsigned short* __restrict__ k_ws)
{
    __shared__ unsigned short pt[64 * PSTR];  // 33,792 B  pixel-major bf16
    __shared__ float red[4][64];

    const int tid  = threadIdx.x;
    const int lane = tid & 63;
    const int wv   = __builtin_amdgcn_readfirstlane(tid >> 6);
    const int t    = blockIdx.y;                    // 0 -> q, 1 -> k

    const float* __restrict__ phi          = t ? phi_rnd : phi_cur;
    const unsigned short* __restrict__ Wbf = t ? wk_bf : wq_bf;
    unsigned short* __restrict__ outp      = t ? k_ws : q_ws;

    const int pgb = blockIdx.x * 64;                // 64-aligned, no b crossing
    const int b   = pgb / HW;
    const int pim = pgb % HW;
    const float* pbase = phi + (size_t)b * CIN * HW + pim;

    const int m = lane & 15, quad = lane >> 4;

    // ---- (1) A-frag preload: issue 16 b128 loads NOW; consumed post-barrier
    short8 af[2][8];
#pragma unroll
    for (int ot = 0; ot < 2; ++ot)
#pragma unroll
        for (int kc = 0; kc < 8; ++kc)
            af[ot][kc] = *(const short8*)(Wbf +
                (size_t)(wv * 32 + ot * 16 + m) * CIN + kc * 32 + quad * 8);

    // ---- (2) stage phi tile: 2 batches x {issue 8 f4 loads, pack+write} ----
#pragma unroll
    for (int half = 0; half < 2; ++half) {
        float4 va[4], vb[4];
#pragma unroll
        for (int p = 0; p < 4; ++p) {
            const int idx = (half * 4 + p) * 256 + tid;
            const int cp  = idx >> 4;          // channel pair 0..127
            const int pq  = idx & 15;          // pixel quad  0..15
            const int c0  = cp * 2;
            va[p] = *(const float4*)(pbase + (size_t)c0 * HW + pq * 4);
            vb[p] = *(const float4*)(pbase + (size_t)(c0 + 1) * HW + pq * 4);
        }
#pragma unroll
        for (int p = 0; p < 4; ++p) {
            const int idx = (half * 4 + p) * 256 + tid;
            const int cp  = idx >> 4;
            const int pq  = idx & 15;
            const int c0  = cp * 2;
            const int swz = ((pq >> 1) & 3) << 3;        // == ((pix>>3)&3)<<3
            const int col = c0 ^ swz;
            *(unsigned*)(pt + (pq * 4 + 0) * PSTR + col) = pkbf(va[p].x, vb[p].x);
            *(unsigned*)(pt + (pq * 4 + 1) * PSTR + col) = pkbf(va[p].y, vb[p].y);
            *(unsigned*)(pt + (pq * 4 + 2) * PSTR + col) = pkbf(va[p].z, vb[p].z);
            *(unsigned*)(pt + (pq * 4 + 3) * PSTR + col) = pkbf(va[p].w, vb[p].w);
        }
    }

    __syncthreads();

    // ---- MFMA: 2 out-tiles x 4 pixel-tiles x K=256 (af already resident) ----
    float4v acc[2][4];
#pragma unroll
    for (int ot = 0; ot < 2; ++ot)
#pragma unroll
        for (int nt = 0; nt < 4; ++nt) acc[ot][nt] = (float4v)0.f;

#pragma unroll
    for (int kc = 0; kc < 8; ++kc) {
        short8 bfr[4];
#pragma unroll
        for (int nt = 0; nt < 4; ++nt) {
            const int row = nt * 16 + m;
            const int col = (kc * 32 + quad * 8) ^ (((row >> 3) & 3) << 3);
            bfr[nt] = *(const short8*)(pt + row * PSTR + col);
        }
#pragma unroll
        for (int nt = 0; nt < 4; ++nt) {
            acc[0][nt] = __builtin_amdgcn_mfma_f32_16x16x32_bf16(af[0][kc], bfr[nt], acc[0][nt], 0, 0, 0);
            acc[1][nt] = __builtin_amdgcn_mfma_f32_16x16x32_bf16(af[1][kc], bfr[nt], acc[1][nt], 0, 0, 0);
        }
    }

    // ---- per-pixel L2 norm: C layout col=lane&15=pixel, row=quad*4+reg=och
#pragma unroll
    for (int nt = 0; nt < 4; ++nt) {
        float ss = 0.f;
#pragma unroll
        for (int ot = 0; ot < 2; ++ot)
#pragma unroll
            for (int r = 0; r < 4; ++r)
                ss = fmaf(acc[ot][nt][r], acc[ot][nt][r], ss);
        ss += __shfl_xor(ss, 16, 64);
        ss += __shfl_xor(ss, 32, 64);
        if (quad == 0) red[wv][nt * 16 + m] = ss;
    }
    __syncthreads();

    float inv[4];
#pragma unroll
    for (int nt = 0; nt < 4; ++nt) {
        const int px = nt * 16 + m;
        const float tot = red[0][px] + red[1][px] + red[2][px] + red[3][px];
        inv[nt] = 1.f / fmaxf(sqrtf(tot), 1e-12f);
    }

    // ---- store bf16 pixel-major ----
#pragma unroll
    for (int nt = 0; nt < 4; ++nt)
#pragma unroll
        for (int ot = 0; ot < 2; ++ot) {
            uint2 st;
            st.x = pkbf(acc[ot][nt][0] * inv[nt], acc[ot][nt][1] * inv[nt]);
            st.y = pkbf(acc[ot][nt][2] * inv[nt], acc[ot][nt][3] * inv[nt]);
            *(uint2*)(outp + (size_t)(pgb + nt * 16 + m) * CMID
                      + wv * 32 + ot * 16 + quad * 4) = st;
        }
}

// ---------------------------------------------------------------------------
// Kernel 2: correlation -- NO INPUT STAGING (q_ws/k_ws are 12.8 MB each,
// L2-resident, freshly written by proj; LDS-staging them was overhead).
// Phase B loads A-frags (q) and B-frags (k) DIRECTLY from global with
// per-lane zero-predication for the halo, 1-deep pipelined.  LDS = 7.4 KB
// (cs + lsf only); ONE barrier.  Geometry + aq/b-frag loads issue first so
// L2 latency overlaps VALU; wq4 loads after the barrier to cap pressure.
// XCD-chunked bijective block swizzle keeps the k halo in-XCD-L2.
// ---------------------------------------------------------------------------
constexpr int TILE = 16;
constexpr int COLS = TILE + 6;      // 22

__global__ __launch_bounds__(256, 4) void corr_kernel(
    const unsigned short* __restrict__ q_ws, const unsigned short* __restrict__ k_ws,
    const float* __restrict__ P_cur, const float* __restrict__ P_rnd,
    const float* __restrict__ wvp, const float* __restrict__ bv,
    const float* __restrict__ gamma_p, float* __restrict__ out)
{
    __shared__ alignas(16) float cs[TILE][52];   // 3,328 B corr vectors
    __shared__ alignas(16) float lsf[TILE][64];  // 4,096 B logit rows

    const int tid  = threadIdx.x;
    const int lane = tid & 63;
    const int wv   = __builtin_amdgcn_readfirstlane(tid >> 6);

    // ---- XCD-chunked bijective swizzle: fid -> contiguous 196-block chunk --
    const int fid = (blockIdx.z * H + blockIdx.y) * (W / TILE) + blockIdx.x;
    const int swz = (fid & 7) * 196 + (fid >> 3);
    const int b   = swz / (H * (W / TILE));
    const int rem = swz % (H * (W / TILE));
    const int h   = rem / (W / TILE);
    const int w0  = (rem % (W / TILE)) * TILE;

    const int m = lane & 15, quad = lane >> 4;

    // ---- A-frags: q rows for the 16 pixels, straight from L2 ----
    const size_t qbase = (size_t)b * HW + h * W + w0;
    short8 aq[4];
#pragma unroll
    for (int kc = 0; kc < 4; ++kc)
        aq[kc] = *(const short8*)(q_ws + (qbase + m) * CMID + kc * 32 + quad * 8);

    // ---- B-frag loader: group g -> k vector (zero for padded halo) ----
    auto loadB = [&](int g, short8* dst) {
        const int r   = g >> 1, nt2 = g & 1;
        const int cc  = nt2 * 16 + m;
        const int hh  = h + r - RAD;
        const int ww  = w0 + cc - RAD;
        const bool ok = (unsigned)hh < (unsigned)H && (unsigned)ww < (unsigned)W
                        && cc < COLS;
        const unsigned short* kp = k_ws
            + ((size_t)b * HW + (ok ? hh * W + ww : 0)) * CMID + quad * 8;
#pragma unroll
        for (int kc = 0; kc < 4; ++kc) {
            short8 v = *(const short8*)(kp + kc * 32);
            dst[kc] = ok ? v : (short8)(short)0;
        }
    };

    short8 bcur[4], bnxt[4];
    loadB(wv, bcur);                              // group 0 in flight

    // zero the cs padding (cols 49..51); ordered by the barrier below
    if (tid < TILE * 3)
        cs[tid / 3][49 + tid % 3] = 0.f;

    // ---- geometry (overlaps the loads above) ----
    const int  ld    = (lane < DD) ? lane : 0;
    const bool valid = (lane < DD);
    const float gamma = gamma_p[0];
    const float bvv   = bv[ld];
    const int dy = ld / KS - RAD;
    const int dx = ld % KS - RAD;
    float geo[4];
#pragma unroll
    for (int i = 0; i < 4; ++i) {
        const int pl = wv * 4 + i;      // pixel local 0..15
        const int hn = h + dy, wn = w0 + pl + dx;
        const bool inb = valid && hn >= 0 && hn < H && wn >= 0 && wn < W;
        const float* pc = P_cur + (size_t)b * 3 * HW + (h * W + w0 + pl);
        const float cx = pc[0], cy = pc[HW], cz = pc[2 * HW];
        float rx = 0.f, ry = 0.f, rz = 0.f;
        if (inb) {
            const float* pr = P_rnd + (size_t)b * 3 * HW + (hn * W + wn);
            rx = pr[0]; ry = pr[HW]; rz = pr[2 * HW];
        }
        const float dpx = cx - rx, dpy = cy - ry, dpz = cz - rz;
        const float dist = sqrtf(fmaxf(dpx * dpx + dpy * dpy + dpz * dpz, 1e-12f));
        geo[i] = gamma * (-dist - 0.5f * fabsf(dpz));
    }

    // ---- phase B: band-GEMM, 1-deep pipelined over the wave's groups ----
#pragma unroll
    for (int gi = 0; gi < 4; ++gi) {
        const int g = wv + gi * 4;
        if (g < 14) {                              // wave-uniform guard
            if (g + 4 < 14) loadB(g + 4, bnxt);
            // 2 independent MFMA chains, then merge
            float4v a0 = (float4v)0.f, a1 = (float4v)0.f;
            a0 = __builtin_amdgcn_mfma_f32_16x16x32_bf16(aq[0], bcur[0], a0, 0, 0, 0);
            a1 = __builtin_amdgcn_mfma_f32_16x16x32_bf16(aq[2], bcur[2], a1, 0, 0, 0);
            a0 = __builtin_amdgcn_mfma_f32_16x16x32_bf16(aq[1], bcur[1], a0, 0, 0, 0);
            a1 = __builtin_amdgcn_mfma_f32_16x16x32_bf16(aq[3], bcur[3], a1, 0, 0, 0);
#pragma unroll
            for (int r4 = 0; r4 < 4; ++r4) a0[r4] += a1[r4];
            // band extract: D row = pixel = quad*4+reg, col cc = (g&1)*16+m
            const int r   = g >> 1;
            const int cc  = (g & 1) * 16 + m;
#pragma unroll
            for (int reg = 0; reg < 4; ++reg) {
                const int p   = quad * 4 + reg;
                const int off = cc - p;            // dx + RAD
                if (off >= 0 && off <= 6)
                    cs[p][r * 7 + off] = a0[reg];
            }
#pragma unroll
            for (int kc = 0; kc < 4; ++kc) bcur[kc] = bnxt[kc];
        }
    }

    __syncthreads();                               // the kernel's ONE barrier

    // ---- phase C1: Wv dot + geo (lane = d); write logit rows to lsf ----
    float4 wq4[13];
#pragma unroll
    for (int j = 0; j < 13; ++j)
        wq4[j] = *(const float4*)(wvp + ld * 52 + j * 4);

#pragma unroll
    for (int i = 0; i < 4; ++i) {
        const int pl = wv * 4 + i;      // pixel local 0..15
        float logit = -INFINITY;
        if (valid) {
            float va0 = bvv, va1 = 0.f;     // dual independent FMA chains
#pragma unroll
            for (int e4 = 0; e4 < 13; ++e4) {
                const float4 c4 = *(const float4*)&cs[pl][e4 * 4];
                const float4 w4 = wq4[e4];
                if (e4 & 1) {
                    va1 = fmaf(w4.x, c4.x, va1);
                    va1 = fmaf(w4.y, c4.y, va1);
                    va1 = fmaf(w4.z, c4.z, va1);
                    va1 = fmaf(w4.w, c4.w, va1);
                } else {
                    va0 = fmaf(w4.x, c4.x, va0);
                    va0 = fmaf(w4.y, c4.y, va0);
                    va0 = fmaf(w4.z, c4.z, va0);
                    va0 = fmaf(w4.w, c4.w, va0);
                }
            }
            logit = (va0 + va1) + geo[i];
        }
        lsf[pl][lane] = logit;          // lanes 49..63 store -inf
    }

    // ---- phase C2: transposed in-wave softmax (lane = pixel x col-quad) ----
    // Same-wave LDS write->read: compiler-ordered via lgkmcnt, no barrier.
    {
        const int pli = lane >> 4;      // 0..3 within wave
        const int dq  = lane & 15;      // column quad (cols dq*4 .. dq*4+3)
        const int pl  = wv * 4 + pli;

        const float4 v = *(const float4*)&lsf[pl][dq * 4];

        float m4 = fmaxf(fmaxf(v.x, v.y), fmaxf(v.z, v.w));
#pragma unroll
        for (int s = 1; s < 16; s <<= 1)
            m4 = fmaxf(m4, __shfl_xor(m4, s, 64));

        const float e0 = __expf(v.x - m4);
        const float e1 = __expf(v.y - m4);
        const float e2 = __expf(v.z - m4);
        const float e3 = __expf(v.w - m4);
        float Z = (e0 + e1) + (e2 + e3);

        // dx = col%7-3, dy = col/7-3  (cols >= 49 have e == 0, values moot)
        const int c0i = dq * 4;
        float dus = 0.f, dvs = 0.f;
        {
            const float ex[4] = { e0, e1, e2, e3 };
#pragma unroll
            for (int j = 0; j < 4; ++j) {
                const int col = c0i + j;
                dus = fmaf(ex[j], (float)(col % KS - RAD), dus);
                dvs = fmaf(ex[j], (float)(col / KS - RAD), dvs);
            }
        }
#pragma unroll
        for (int s = 1; s < 16; s <<= 1) {
            Z   += __shfl_xor(Z,   s, 64);
            dus += __shfl_xor(dus, s, 64);
            dvs += __shfl_xor(dvs, s, 64);
        }

        if (dq == 0) {
            const int pg = b * HW + h * W + w0 + pl;
            const float invZ = 1.f / Z;
            out[pg]            = dus * invZ;
            out[NPIX + pg]     = dvs * invZ;
            out[2 * NPIX + pg] = invZ;       // conf = max w = exp(lmax-lmax)/Z
        }
    }
}

// ---------------------------------------------------------------------------
extern "C" void kernel_launch(void* const* d_in, const int* in_sizes, int n_in,
                              void* d_out, int out_size, void* d_ws, size_t ws_size,
                              hipStream_t stream)
{
    const float* phi_cur = (const float*)d_in[0];
    const float* phi_rnd = (const float*)d_in[1];
    const float* P_cur   = (const float*)d_in[2];
    const float* P_rnd   = (const float*)d_in[3];
    const float* Wq      = (const float*)d_in[4];
    const float* Wk      = (const float*)d_in[5];
    const float* Wv      = (const float*)d_in[6];
    const float* bv      = (const float*)d_in[7];
    const float* gm      = (const float*)d_in[8];
    float* out = (float*)d_out;

    unsigned short* ws   = (unsigned short*)d_ws;
    unsigned short* q_ws = ws;                                  // NPIX*CMID bf16
    unsigned short* k_ws = q_ws + (size_t)NPIX * CMID;          // NPIX*CMID bf16
    unsigned short* wqb  = k_ws + (size_t)NPIX * CMID;          // CMID*CIN bf16
    unsigned short* wkb  = wqb + (size_t)CMID * CIN;
    float*          wvp  = (float*)(wkb + (size_t)CMID * CIN);  // 49x52 f32 (16B-aligned)

    prep<<<dim3(65), 256, 0, stream>>>(Wq, Wk, Wv, wqb, wkb, wvp);

    proj_mfma<<<dim3(NPIX / 64, 2), 256, 0, stream>>>(
        phi_cur, phi_rnd, wqb, wkb, q_ws, k_ws);

    corr_kernel<<<dim3(W / TILE, H, B), 256, 0, stream>>>(
        q_ws, k_ws, P_cur, P_rnd, wvp, bv, gm, out);
}

// Round 8
// 130.602 us; speedup vs baseline: 1.0712x; 1.0537x over previous
//
#include <hip/hip_runtime.h>
#include <hip/hip_bf16.h>
#include <math.h>

// Problem constants (B, Cin, Cmid, H, W) = (2, 256, 128, 112, 112), R=3
constexpr int B    = 2;
constexpr int CIN  = 256;
constexpr int CMID = 128;
constexpr int H    = 112;
constexpr int W    = 112;
constexpr int HW   = H * W;        // 12544
constexpr int NPIX = B * HW;       // 25088
constexpr int RAD  = 3;
constexpr int KS   = 7;
constexpr int DD   = 49;

typedef __attribute__((ext_vector_type(8))) short  short8;   // 8 bf16 (4 VGPR)
typedef __attribute__((ext_vector_type(4))) float  float4v;  // MFMA C/D

// RNE fp32-pair -> packed bf16x2 via v_cvt_pk_bf16_f32 (compiler-lowered)
__device__ __forceinline__ unsigned pkbf(float a, float b) {
    __hip_bfloat162 h = __float22bfloat162_rn(make_float2(a, b));
    union { __hip_bfloat162 h2; unsigned u; } c;
    c.h2 = h;
    return c.u;
}

// ---------------------------------------------------------------------------
// Kernel 0 (prep, tiny): Wq/Wk f32 -> bf16; Wv f32 -> padded f32 [49][52].
// Kept SEPARATE (R6 fold regressed: VGPR spill past the 128 cap in proj).
// ---------------------------------------------------------------------------
__global__ __launch_bounds__(256) void prep(
    const float* __restrict__ Wq, const float* __restrict__ Wk,
    const float* __restrict__ Wv,
    unsigned short* __restrict__ wqb, unsigned short* __restrict__ wkb,
    float* __restrict__ wvp)
{
    if (blockIdx.x < 64) {
        const int i  = blockIdx.x * 256 + threadIdx.x;   // float4 index
        const int n4 = (CMID * CIN) / 4;                 // 8192 per matrix
        const float4 v = (i < n4) ? ((const float4*)Wq)[i] : ((const float4*)Wk)[i - n4];
        uint2 r;
        r.x = pkbf(v.x, v.y);
        r.y = pkbf(v.z, v.w);
        if (i < n4) ((uint2*)wqb)[i] = r;
        else        ((uint2*)wkb)[i - n4] = r;
    } else {
        for (int idx = threadIdx.x; idx < DD * 52; idx += 256) {
            const int r = idx / 52, c = idx % 52;
            wvp[idx] = (c < DD) ? Wv[r * DD + c] : 0.f;
        }
    }
}

// ---------------------------------------------------------------------------
// Kernel 1: q = l2norm(Wq @ phi_cur), k = l2norm(Wk @ phi_rnd)  via bf16 MFMA.
// EXACT R5 kernel (best measured, 132.4):
//  (1) A-frags (16 x b128, L2-hot bf16 W) issued FIRST -- compiler cannot
//      hoist loads across __syncthreads; pre-barrier issue hides ~200cyc
//      under staging + barrier wait.  K-loop pure {4 ds_read + 8 MFMA}.
//  (2) staging split issue-early/write-late (T14): 2 batches of 8 float4
//      loads in flight, then pack/write.
// LDS: pixel-major bf16, PSTR=264, col XOR-swizzle ((pix>>3)&3)<<3.
// __launch_bounds__(256,4): 4 blocks/CU, all 784 co-resident.
// ---------------------------------------------------------------------------
constexpr int PSTR = 264;           // shorts per pixel row in pt

__global__ __launch_bounds__(256, 4) void proj_mfma(
    const float* __restrict__ phi_cur, const float* __restrict__ phi_rnd,
    const unsigned short* __restrict__ wq_bf, const unsigned short* __restrict__ wk_bf,
    unsigned short* __restrict__ q_ws, unsigned short* __restrict__ k_ws)
{
    __shared__ unsigned short pt[64 * PSTR];  // 33,792 B  pixel-major bf16
    __shared__ float red[4][64];

    const int tid  = threadIdx.x;
    const int lane = tid & 63;
    const int wv   = __builtin_amdgcn_readfirstlane(tid >> 6);
    const int t    = blockIdx.y;                    // 0 -> q, 1 -> k

    const float* __restrict__ phi          = t ? phi_rnd : phi_cur;
    const unsigned short* __restrict__ Wbf = t ? wk_bf : wq_bf;
    unsigned short* __restrict__ outp      = t ? k_ws : q_ws;

    const int pgb = blockIdx.x * 64;                // 64-aligned, no b crossing
    const int b   = pgb / HW;
    const int pim = pgb % HW;
    const float* pbase = phi + (size_t)b * CIN * HW + pim;

    const int m = lane & 15, quad = lane >> 4;

    // ---- (1) A-frag preload: issue 16 b128 loads NOW; consumed post-barrier
    short8 af[2][8];
#pragma unroll
    for (int ot = 0; ot < 2; ++ot)
#pragma unroll
        for (int kc = 0; kc < 8; ++kc)
            af[ot][kc] = *(const short8*)(Wbf +
                (size_t)(wv * 32 + ot * 16 + m) * CIN + kc * 32 + quad * 8);

    // ---- (2) stage phi tile: 2 batches x {issue 8 f4 loads, pack+write} ----
#pragma unroll
    for (int half = 0; half < 2; ++half) {
        float4 va[4], vb[4];
#pragma unroll
        for (int p = 0; p < 4; ++p) {
            const int idx = (half * 4 + p) * 256 + tid;
            const int cp  = idx >> 4;          // channel pair 0..127
            const int pq  = idx & 15;          // pixel quad  0..15
            const int c0  = cp * 2;
            va[p] = *(const float4*)(pbase + (size_t)c0 * HW + pq * 4);
            vb[p] = *(const float4*)(pbase + (size_t)(c0 + 1) * HW + pq * 4);
        }
#pragma unroll
        for (int p = 0; p < 4; ++p) {
            const int idx = (half * 4 + p) * 256 + tid;
            const int cp  = idx >> 4;
            const int pq  = idx & 15;
            const int c0  = cp * 2;
            const int swz = ((pq >> 1) & 3) << 3;        // == ((pix>>3)&3)<<3
            const int col = c0 ^ swz;
            *(unsigned*)(pt + (pq * 4 + 0) * PSTR + col) = pkbf(va[p].x, vb[p].x);
            *(unsigned*)(pt + (pq * 4 + 1) * PSTR + col) = pkbf(va[p].y, vb[p].y);
            *(unsigned*)(pt + (pq * 4 + 2) * PSTR + col) = pkbf(va[p].z, vb[p].z);
            *(unsigned*)(pt + (pq * 4 + 3) * PSTR + col) = pkbf(va[p].w, vb[p].w);
        }
    }

    __syncthreads();

    // ---- MFMA: 2 out-tiles x 4 pixel-tiles x K=256 (af already resident) ----
    float4v acc[2][4];
#pragma unroll
    for (int ot = 0; ot < 2; ++ot)
#pragma unroll
        for (int nt = 0; nt < 4; ++nt) acc[ot][nt] = (float4v)0.f;

#pragma unroll
    for (int kc = 0; kc < 8; ++kc) {
        short8 bfr[4];
#pragma unroll
        for (int nt = 0; nt < 4; ++nt) {
            const int row = nt * 16 + m;
            const int col = (kc * 32 + quad * 8) ^ (((row >> 3) & 3) << 3);
            bfr[nt] = *(const short8*)(pt + row * PSTR + col);
        }
#pragma unroll
        for (int nt = 0; nt < 4; ++nt) {
            acc[0][nt] = __builtin_amdgcn_mfma_f32_16x16x32_bf16(af[0][kc], bfr[nt], acc[0][nt], 0, 0, 0);
            acc[1][nt] = __builtin_amdgcn_mfma_f32_16x16x32_bf16(af[1][kc], bfr[nt], acc[1][nt], 0, 0, 0);
        }
    }

    // ---- per-pixel L2 norm: C layout col=lane&15=pixel, row=quad*4+reg=och
#pragma unroll
    for (int nt = 0; nt < 4; ++nt) {
        float ss = 0.f;
#pragma unroll
        for (int ot = 0; ot < 2; ++ot)
#pragma unroll
            for (int r = 0; r < 4; ++r)
                ss = fmaf(acc[ot][nt][r], acc[ot][nt][r], ss);
        ss += __shfl_xor(ss, 16, 64);
        ss += __shfl_xor(ss, 32, 64);
        if (quad == 0) red[wv][nt * 16 + m] = ss;
    }
    __syncthreads();

    float inv[4];
#pragma unroll
    for (int nt = 0; nt < 4; ++nt) {
        const int px = nt * 16 + m;
        const float tot = red[0][px] + red[1][px] + red[2][px] + red[3][px];
        inv[nt] = 1.f / fmaxf(sqrtf(tot), 1e-12f);
    }

    // ---- store bf16 pixel-major ----
#pragma unroll
    for (int nt = 0; nt < 4; ++nt)
#pragma unroll
        for (int ot = 0; ot < 2; ++ot) {
            uint2 st;
            st.x = pkbf(acc[ot][nt][0] * inv[nt], acc[ot][nt][1] * inv[nt]);
            st.y = pkbf(acc[ot][nt][2] * inv[nt], acc[ot][nt][3] * inv[nt]);
            *(uint2*)(outp + (size_t)(pgb + nt * 16 + m) * CMID
                      + wv * 32 + ot * 16 + quad * 4) = st;
        }
}

// ---------------------------------------------------------------------------
// Kernel 2: correlation via MFMA band-GEMM + Wv + geometry + softmax.
// R5's STAGED corr (R7 proved staged > L2-direct by 5.2us: 10-deep issue of
// the phase-A loads amortizes L2 latency once; the direct path paid ~4
// serial L2 round-trips per wave).  Phase A issue-early/write-late; hoisted
// geometry; XCD-chunked bijective swizzle; 2 barriers.
// Phase B micro-edits this round (R7 lesson, zero-risk):
//  - A-frags explicitly hoisted out of the group loop (loop-invariant).
//  - dual accumulators break the 4-long dependent MFMA chain into 2x2.
// __launch_bounds__(256,3): LDS-limited 3 blocks/CU preserved.
// ---------------------------------------------------------------------------
constexpr int TILE = 16;
constexpr int COLS = TILE + 6;      // 22
constexpr int NV   = KS * COLS;     // 154 staged pixel-vectors
constexpr int KSTR = 136;           // shorts per vector in LDS (272 B)

__global__ __launch_bounds__(256, 3) void corr_kernel(
    const unsigned short* __restrict__ q_ws, const unsigned short* __restrict__ k_ws,
    const float* __restrict__ P_cur, const float* __restrict__ P_rnd,
    const float* __restrict__ wvp, const float* __restrict__ bv,
    const float* __restrict__ gamma_p, float* __restrict__ out)
{
    __shared__ unsigned short kt[NV * KSTR];                 // 41,888 B
    __shared__ alignas(16) unsigned short qt[TILE * KSTR];   //  4,352 B (ls overlay)
    __shared__ float cs[TILE][52];                           //  3,328 B corr vectors

    const int tid  = threadIdx.x;
    const int lane = tid & 63;
    const int wv   = __builtin_amdgcn_readfirstlane(tid >> 6);

    // ---- XCD-chunked bijective swizzle: fid -> contiguous 196-block chunk --
    const int fid = (blockIdx.z * H + blockIdx.y) * (W / TILE) + blockIdx.x;
    const int swz = (fid & 7) * 196 + (fid >> 3);
    const int b   = swz / (H * (W / TILE));
    const int rem = swz % (H * (W / TILE));
    const int h   = rem / (W / TILE);
    const int w0  = (rem % (W / TILE)) * TILE;

    // ---- phase A: ISSUE all staging loads into registers first ----
    const int sub  = tid & 15;
    const int vgrp = tid >> 4;          // 0..15
    uint4 stv[10];
#pragma unroll
    for (int pass = 0; pass < 10; ++pass) {
        const int vi = pass * 16 + vgrp;
        uint4 v = make_uint4(0, 0, 0, 0);
        if (vi < NV) {
            const int rr = vi / COLS;
            const int cc = vi % COLS;
            const int hh = h + rr - RAD;
            const int ww = w0 + cc - RAD;
            if (hh >= 0 && hh < H && ww >= 0 && ww < W)
                v = *(const uint4*)(k_ws + (size_t)(b * HW + hh * W + ww) * CMID + sub * 8);
        }
        stv[pass] = v;
    }
    const uint4 qv = *(const uint4*)(q_ws + (size_t)(b * HW + h * W + w0 + vgrp) * CMID + sub * 8);

    // ---- per-lane constants + HOISTED GEOMETRY (overlap staging loads) ----
    const int  ld    = (lane < DD) ? lane : 0;
    const bool valid = (lane < DD);
    float4 wq4[13];
#pragma unroll
    for (int j = 0; j < 13; ++j)
        wq4[j] = *(const float4*)(wvp + ld * 52 + j * 4);
    const float bvv   = bv[ld];
    const float gamma = gamma_p[0];

    const int dy = ld / KS - RAD;
    const int dx = ld % KS - RAD;
    float geo[4];
#pragma unroll
    for (int i = 0; i < 4; ++i) {
        const int pl = wv * 4 + i;      // pixel local 0..15
        const int hn = h + dy, wn = w0 + pl + dx;
        const bool inb = valid && hn >= 0 && hn < H && wn >= 0 && wn < W;
        const float* pc = P_cur + (size_t)b * 3 * HW + (h * W + w0 + pl);
        const float cx = pc[0], cy = pc[HW], cz = pc[2 * HW];
        float rx = 0.f, ry = 0.f, rz = 0.f;
        if (inb) {
            const float* pr = P_rnd + (size_t)b * 3 * HW + (hn * W + wn);
            rx = pr[0]; ry = pr[HW]; rz = pr[2 * HW];
        }
        const float dpx = cx - rx, dpy = cy - ry, dpz = cz - rz;
        const float dist = sqrtf(fmaxf(dpx * dpx + dpy * dpy + dpz * dpz, 1e-12f));
        geo[i] = gamma * (-dist - 0.5f * fabsf(dpz));
    }

    // ---- phase A: LDS writes (waits only on the k/q loads) ----
#pragma unroll
    for (int pass = 0; pass < 10; ++pass) {
        const int vi = pass * 16 + vgrp;
        if (vi < NV)
            *(uint4*)(kt + vi * KSTR + sub * 8) = stv[pass];
    }
    *(uint4*)(qt + vgrp * KSTR + sub * 8) = qv;

    __syncthreads();

    // zero the cs padding (cols 49..51) so phase C1's 0*pad stays 0
    if (tid < TILE * 3)
        cs[tid / 3][49 + tid % 3] = 0.f;

    // ---- phase B: MFMA band-GEMM (A-frags hoisted; dual accumulators) ----
    const int m = lane & 15, quad = lane >> 4;
    short8 aqf[4];
#pragma unroll
    for (int kc = 0; kc < 4; ++kc)
        aqf[kc] = *(const short8*)(qt + m * KSTR + kc * 32 + quad * 8);

    for (int g = wv; g < 14; g += 4) {
        const int r  = g >> 1;
        const int nt = g & 1;
        const int vi = min(r * COLS + nt * 16 + m, NV - 1);  // clamp OOB cols
        const short8 b0 = *(const short8*)(kt + vi * KSTR + 0 * 32 + quad * 8);
        const short8 b1 = *(const short8*)(kt + vi * KSTR + 1 * 32 + quad * 8);
        const short8 b2 = *(const short8*)(kt + vi * KSTR + 2 * 32 + quad * 8);
        const short8 b3 = *(const short8*)(kt + vi * KSTR + 3 * 32 + quad * 8);
        float4v a0 = (float4v)0.f, a1 = (float4v)0.f;
        a0 = __builtin_amdgcn_mfma_f32_16x16x32_bf16(aqf[0], b0, a0, 0, 0, 0);
        a1 = __builtin_amdgcn_mfma_f32_16x16x32_bf16(aqf[1], b1, a1, 0, 0, 0);
        a0 = __builtin_amdgcn_mfma_f32_16x16x32_bf16(aqf[2], b2, a0, 0, 0, 0);
        a1 = __builtin_amdgcn_mfma_f32_16x16x32_bf16(aqf[3], b3, a1, 0, 0, 0);
#pragma unroll
        for (int r4 = 0; r4 < 4; ++r4) a0[r4] += a1[r4];
        // band extract: D row = pixel = quad*4+reg, col cc = nt*16 + m
#pragma unroll
        for (int reg = 0; reg < 4; ++reg) {
            const int p   = quad * 4 + reg;
            const int off = nt * 16 + m - p;     // dx + RAD
            if (off >= 0 && off <= 6)
                cs[p][r * 7 + off] = a0[reg];
        }
    }
    __syncthreads();
    // qt is dead from here on -> overlay ls (16 rows x 64 f32 = 4,096 B)
    float* lsf = reinterpret_cast<float*>(qt);

    // ---- phase C1: pure dot + add (lane = d); write logit rows to ls ----
#pragma unroll
    for (int i = 0; i < 4; ++i) {
        const int pl = wv * 4 + i;      // pixel local 0..15
        float logit = -INFINITY;
        if (valid) {
            float va0 = bvv, va1 = 0.f;     // dual independent FMA chains
#pragma unroll
            for (int e4 = 0; e4 < 13; ++e4) {
                const float4 c4 = *(const float4*)&cs[pl][e4 * 4];
                const float4 w4 = wq4[e4];
                if (e4 & 1) {
                    va1 = fmaf(w4.x, c4.x, va1);
                    va1 = fmaf(w4.y, c4.y, va1);
                    va1 = fmaf(w4.z, c4.z, va1);
                    va1 = fmaf(w4.w, c4.w, va1);
                } else {
                    va0 = fmaf(w4.x, c4.x, va0);
                    va0 = fmaf(w4.y, c4.y, va0);
                    va0 = fmaf(w4.z, c4.z, va0);
                    va0 = fmaf(w4.w, c4.w, va0);
                }
            }
            logit = (va0 + va1) + geo[i];
        }
        lsf[pl * 64 + lane] = logit;    // lanes 49..63 store -inf
    }

    // ---- phase C2: transposed in-wave softmax (lane = pixel x col-quad) ----
    // Same-wave LDS write->read: compiler-ordered via lgkmcnt, no barrier.
    {
        const int pli = lane >> 4;      // 0..3 within wave
        const int dq  = lane & 15;      // column quad (cols dq*4 .. dq*4+3)
        const int pl  = wv * 4 + pli;

        const float4 v = ((const float4*)lsf)[pl * 16 + dq];

        float m4 = fmaxf(fmaxf(v.x, v.y), fmaxf(v.z, v.w));
#pragma unroll
        for (int s = 1; s < 16; s <<= 1)
            m4 = fmaxf(m4, __shfl_xor(m4, s, 64));

        const float e0 = __expf(v.x - m4);
        const float e1 = __expf(v.y - m4);
        const float e2 = __expf(v.z - m4);
        const float e3 = __expf(v.w - m4);
        float Z = (e0 + e1) + (e2 + e3);

        // dx = col%7-3, dy = col/7-3  (cols >= 49 have e == 0, values moot)
        const int c0i = dq * 4;
        float dus = 0.f, dvs = 0.f;
        {
            const float ex[4] = { e0, e1, e2, e3 };
#pragma unroll
            for (int j = 0; j < 4; ++j) {
                const int col = c0i + j;
                dus = fmaf(ex[j], (float)(col % KS - RAD), dus);
                dvs = fmaf(ex[j], (float)(col / KS - RAD), dvs);
            }
        }
#pragma unroll
        for (int s = 1; s < 16; s <<= 1) {
            Z   += __shfl_xor(Z,   s, 64);
            dus += __shfl_xor(dus, s, 64);
            dvs += __shfl_xor(dvs, s, 64);
        }

        if (dq == 0) {
            const int pg = b * HW + h * W + w0 + pl;
            const float invZ = 1.f / Z;
            out[pg]            = dus * invZ;
            out[NPIX + pg]     = dvs * invZ;
            out[2 * NPIX + pg] = invZ;       // conf = max w = exp(lmax-lmax)/Z
        }
    }
}

// ---------------------------------------------------------------------------
extern "C" void kernel_launch(void* const* d_in, const int* in_sizes, int n_in,
                              void* d_out, int out_size, void* d_ws, size_t ws_size,
                              hipStream_t stream)
{
    const float* phi_cur = (const float*)d_in[0];
    const float* phi_rnd = (const float*)d_in[1];
    const float* P_cur   = (const float*)d_in[2];
    const float* P_rnd   = (const float*)d_in[3];
    const float* Wq      = (const float*)d_in[4];
    const float* Wk      = (const float*)d_in[5];
    const float* Wv      = (const float*)d_in[6];
    const float* bv      = (const float*)d_in[7];
    const float* gm      = (const float*)d_in[8];
    float* out = (float*)d_out;

    unsigned short* ws   = (unsigned short*)d_ws;
    unsigned short* q_ws = ws;                                  // NPIX*CMID bf16
    unsigned short* k_ws = q_ws + (size_t)NPIX * CMID;          // NPIX*CMID bf16
    unsigned short* wqb  = k_ws + (size_t)NPIX * CMID;          // CMID*CIN bf16
    unsigned short* wkb  = wqb + (size_t)CMID * CIN;
    float*          wvp  = (float*)(wkb + (size_t)CMID * CIN);  // 49x52 f32 (16B-aligned)

    prep<<<dim3(65), 256, 0, stream>>>(Wq, Wk, Wv, wqb, wkb, wvp);

    proj_mfma<<<dim3(NPIX / 64, 2), 256, 0, stream>>>(
        phi_cur, phi_rnd, wqb, wkb, q_ws, k_ws);

    corr_kernel<<<dim3(W / TILE, H, B), 256, 0, stream>>>(
        q_ws, k_ws, P_cur, P_rnd, wvp, bv, gm, out);
}